// Round 1
// baseline (109.551 us; speedup 1.0000x reference)
//
#include <hip/hip_runtime.h>
#include <stdint.h>

#define HH 512
#define WW 512
#define PLANE (HH*WW)
#define NCH 20

// dens[] = {1,4,3,2,0,4,4,0,4,3,3,2,3,4}, packed 4 bits per element
#define DENS_PACK 0x43233404402341ULL
// grav[] = {1,0,1,1,1,0,0,1,0,1,1,1,1,0}, packed 1 bit per element
#define GRAV_PACK 0x1E9Du

__device__ __forceinline__ int dens_of(int e) {
    return (int)((DENS_PACK >> (e * 4)) & 0xFULL);
}

// ---------------- Kernel 1: extract eid+grav byte grid ----------------
__global__ __launch_bounds__(256) void extract_k(const float* __restrict__ world,
                                                 uint32_t* __restrict__ st) {
    int idx = blockIdx.x * 256 + threadIdx.x;      // 0 .. 524287 (4 cells each)
    int b  = idx >> 16;                            // PLANE/4 = 65536 float4 per batch
    int p4 = idx & 0xFFFF;
    const float4* base = (const float4*)(world + (size_t)b * NCH * PLANE) + p4;
    int e0 = 0, e1 = 0, e2 = 0, e3 = 0;
#pragma unroll
    for (int c = 1; c < 14; ++c) {                 // c=0 contributes eid 0 (init)
        float4 v = base[c * (PLANE / 4)];
        if (v.x != 0.0f) e0 = c;
        if (v.y != 0.0f) e1 = c;
        if (v.z != 0.0f) e2 = c;
        if (v.w != 0.0f) e3 = c;
    }
    uint32_t b0 = (uint32_t)(e0 | (((GRAV_PACK >> e0) & 1u) << 4));
    uint32_t b1 = (uint32_t)(e1 | (((GRAV_PACK >> e1) & 1u) << 4));
    uint32_t b2 = (uint32_t)(e2 | (((GRAV_PACK >> e2) & 1u) << 4));
    uint32_t b3 = (uint32_t)(e3 | (((GRAV_PACK >> e3) & 1u) << 4));
    st[idx] = b0 | (b1 << 8) | (b2 << 16) | (b3 << 24);
}

// ---------------- Kernel 2: simulate 9 passes on bytes, expand ----------------
#define TILE_H 64
#define TILE_W 64
#define HALO_H 9
#define HALO_W 5
#define RH (TILE_H + 2*HALO_H)   // 82
#define RW (TILE_W + 2*HALO_W)   // 74
#define RWS 76                   // LDS row stride
#define NREG (RH*RW)             // 6068

__global__ __launch_bounds__(256) void sim_k(const uint8_t* __restrict__ st_in,
                                             const float* __restrict__ rnd,
                                             float* __restrict__ out) {
    __shared__ uint8_t bufA[RH * RWS];
    __shared__ uint8_t bufB[RH * RWS];
    __shared__ uint8_t aux [RH * RWS];   // bit0 = fall_dir, bit1 = did_gravity

    const int tid = threadIdx.x;
    const int b   = blockIdx.z;
    const int h0  = blockIdx.y * TILE_H;
    const int w0  = blockIdx.x * TILE_W;
    const uint8_t* stb = st_in + b * PLANE;
    const float*   rb  = rnd   + b * PLANE;

    // ---- load region (torus wrap) ----
    for (int r = tid; r < NREG; r += 256) {
        int i = r / RW, j = r - i * RW;
        int gh = (h0 + i - HALO_H) & (HH - 1);
        int gw = (w0 + j - HALO_W) & (WW - 1);
        int gi = gh * WW + gw;
        bufA[i * RWS + j] = stb[gi];
        aux [i * RWS + j] = (rb[gi] > 0.5f) ? 1 : 0;
    }
    __syncthreads();

    // ---- pass 0: stone support / gravity update (ZERO-padded, not wrapped) ----
    for (int r = tid; r < NREG; r += 256) {
        int i = r / RW, j = r - i * RW;
        uint8_t s  = bufA[i * RWS + j];
        uint8_t ns = s;
        if ((s & 15) == 9) {
            int gh = (h0 + i - HALO_H) & (HH - 1);
            int gw = (w0 + j - HALO_W) & (WW - 1);
            int sup = 0;
            if (gh != 0) {
                int im = (i > 0) ? i - 1 : 0;                      // clamp: halo-garbage ok
                if (gw != 0) {
                    int jl = (j > 0) ? j - 1 : 0;
                    sup += ((bufA[im * RWS + jl] & 15) == 9);
                }
                if (gw != WW - 1) {
                    int jr = (j < RW - 1) ? j + 1 : RW - 1;
                    sup += ((bufA[im * RWS + jr] & 15) == 9);
                }
            }
            ns = (uint8_t)(9 | ((sup < 2) ? 16 : 0));
        }
        bufB[i * RWS + j] = ns;
    }
    __syncthreads();

    uint8_t* cur = bufB;
    uint8_t* nxt = bufA;

    // ---- passes 1..4: vertical gravity, curr_density = 0..3 ----
    for (int curr = 0; curr < 4; ++curr) {
        for (int r = tid; r < NREG; r += 256) {
            int i = r / RW, j = r - i * RW;
            int ia = (i > 0) ? i - 1 : 0;
            int ib = (i < RH - 1) ? i + 1 : RH - 1;
            uint8_t s  = cur[i  * RWS + j];
            uint8_t sa = cur[ia * RWS + j];
            uint8_t sb = cur[ib * RWS + j];
            int d  = dens_of(s  & 15);
            int da = dens_of(sa & 15);
            int db = dens_of(sb & 15);
            int g  = (s  >> 4) & 1;
            int ga = (sa >> 4) & 1;
            int gb = (sb >> 4) & 1;
            bool bel = (d == curr) && (d > db) && gb && g;    // take value from below
            bool abv = (da > d) && (da == curr) && ga && g;   // take value from above
            nxt[i * RWS + j] = bel ? sb : (abv ? sa : s);
            if (abv) aux[i * RWS + j] |= 2;                   // did_gravity (positional)
        }
        __syncthreads();
        uint8_t* t = cur; cur = nxt; nxt = t;
    }

    // ---- passes 5..8: diagonal falls, (elem, dir) = (2,L),(2,R),(12,L),(12,R) ----
    for (int pass = 0; pass < 4; ++pass) {
        const int  elem = (pass < 2) ? 2 : 12;
        const bool fl   = ((pass & 1) == 0);
        const int  dj   = fl ? -1 : 1;          // "below-left" col offset
        for (int r = tid; r < NREG; r += 256) {
            int i = r / RW, j = r - i * RW;
            int ia = (i > 0) ? i - 1 : 0;
            int ib = (i < RH - 1) ? i + 1 : RH - 1;
            int jb = j + dj; jb = (jb < 0) ? 0 : ((jb > RW - 1) ? RW - 1 : jb);
            int ja = j - dj; ja = (ja < 0) ? 0 : ((ja > RW - 1) ? RW - 1 : ja);
            uint8_t s   = cur[i  * RWS + j];
            uint8_t sbl = cur[ib * RWS + jb];
            uint8_t sar = cur[ia * RWS + ja];
            uint8_t ax  = aux[i  * RWS + j];
            uint8_t abl = aux[ib * RWS + jb];
            uint8_t aar = aux[ia * RWS + ja];
            int d   = dens_of(s   & 15);
            int dbl = dens_of(sbl & 15);
            int dar = dens_of(sar & 15);
            int g   = (s   >> 4) & 1;
            int gbl = (sbl >> 4) & 1;
            int gar = (sar >> 4) & 1;
            int ndg   = !(ax  & 2);
            int ndgbl = !(abl & 2);
            int ndgar = !(aar & 2);
            int mt  = fl ? (ax  & 1) : !(ax  & 1);
            int mta = fl ? (aar & 1) : !(aar & 1);
            bool bbl = ((s   & 15) == elem) && ndgbl && ndg && mt  && (d   > dbl) && gbl && g;
            bool bar = ((sar & 15) == elem) && ndgar && ndg && mta && (dar > d)   && gar && g;
            nxt[i * RWS + j] = bbl ? sbl : (bar ? sar : s);
        }
        __syncthreads();
        uint8_t* t = cur; cur = nxt; nxt = t;
    }

    // ---- expand core 64x64 to 20 f32 channels ----
    const int lane = tid & 63;
    const int wv   = tid >> 6;            // 4 waves
    const int roff = lane >> 4;           // 0..3
    const int col  = (lane & 15) * 4;     // 0,4,..,60
    float* ob = out + (size_t)b * NCH * PLANE;
    for (int pair = wv; pair < NCH * 16; pair += 4) {
        int c   = pair >> 4;              // channel 0..19 (uniform per wave)
        int rg  = pair & 15;
        int row = rg * 4 + roff;
        const uint8_t* p = &cur[(HALO_H + row) * RWS + HALO_W + col];
        float4 v;
        float* vv = &v.x;
#pragma unroll
        for (int q = 0; q < 4; ++q) {
            uint8_t s = p[q];
            int e = s & 15;
            float val;
            if (c < 14)       val = (e == c) ? 1.0f : 0.0f;
            else if (c == 14) val = (float)dens_of(e);
            else if (c == 15) val = (float)((s >> 4) & 1);
            else              val = 0.0f;
            vv[q] = val;
        }
        *(float4*)(ob + (size_t)c * PLANE + (size_t)(h0 + row) * WW + (w0 + col)) = v;
    }
}

extern "C" void kernel_launch(void* const* d_in, const int* in_sizes, int n_in,
                              void* d_out, int out_size, void* d_ws, size_t ws_size,
                              hipStream_t stream) {
    const float* world = (const float*)d_in[0];
    const float* rnd   = (const float*)d_in[1];
    float* out = (float*)d_out;
    uint32_t* st = (uint32_t*)d_ws;   // 2 MB byte grid

    extract_k<<<2048, 256, 0, stream>>>(world, st);

    dim3 grid(WW / TILE_W, HH / TILE_H, 8);
    sim_k<<<grid, 256, 0, stream>>>((const uint8_t*)st, rnd, out);
}

// Round 2
// 64.135 us; speedup vs baseline: 1.7081x; 1.7081x over previous
//
#include <hip/hip_runtime.h>
#include <stdint.h>

#define HH 512
#define WW 512
#define PLANE (HH*WW)
#define NCH 20

// dens[] = {1,4,3,2,0,4,4,0,4,3,3,2,3,4}, 4 bits per element
#define DENS_PACK 0x43233404402341ULL
// grav[] = {1,0,1,1,1,0,0,1,0,1,1,1,1,0}, 1 bit per element
#define GRAV_PACK 0x1E9Du

__device__ __forceinline__ int dens_of(int e) {
    return (int)((DENS_PACK >> (e * 4)) & 0xFULL);
}

// ---------------- SWAR helpers (per-byte lanes) ----------------
// x has <=4-bit fields per byte; returns 0x01 in each byte where field == 0
__device__ __forceinline__ uint32_t eqz4(uint32_t x) {
    uint32_t nz = (x | (x >> 1) | (x >> 2) | (x >> 3)) & 0x01010101u;
    return nz ^ 0x01010101u;
}
// per-byte a > b for values 0..7 (3-bit); returns 0/1 per byte
__device__ __forceinline__ uint32_t gtb(uint32_t a, uint32_t b) {
    uint32_t t = (a | 0x08080808u) - b;          // 8 + a - b in [4,12], no borrow
    return ((t + 0x07070707u) & 0x10101010u) >> 4; // >=16 iff a>b
}
// 0/1 per byte -> 0x00/0xFF per byte
__device__ __forceinline__ uint32_t bmask(uint32_t b) {
    uint32_t h = b << 7;
    return (h - (h >> 7)) | h;
}

// ---------------- Kernel 1: pack eid|grav<<4|dens<<5 per cell ----------------
__global__ __launch_bounds__(256) void extract_k(const float* __restrict__ world,
                                                 uint32_t* __restrict__ st) {
    int idx = blockIdx.x * 256 + threadIdx.x;      // 4 cells each
    int b  = idx >> 16;
    int p4 = idx & 0xFFFF;
    const float4* base = (const float4*)(world + (size_t)b * NCH * PLANE) + p4;
    int e0 = 0, e1 = 0, e2 = 0, e3 = 0;
#pragma unroll
    for (int c = 1; c < 14; ++c) {
        float4 v = base[c * (PLANE / 4)];
        if (v.x != 0.0f) e0 = c;
        if (v.y != 0.0f) e1 = c;
        if (v.z != 0.0f) e2 = c;
        if (v.w != 0.0f) e3 = c;
    }
#define PACK(e) ((uint32_t)((e) | (((GRAV_PACK >> (e)) & 1u) << 4) | (dens_of(e) << 5)))
    st[idx] = PACK(e0) | (PACK(e1) << 8) | (PACK(e2) << 16) | (PACK(e3) << 24);
#undef PACK
}

// ---------------- Kernel 2: 9 SWAR passes + expand ----------------
#define TILE 64
#define HALO_H 9
#define HALO_W 8                 // bytes; word-aligned halo
#define RH (TILE + 2*HALO_H)     // 82 rows
#define RWW 20                   // words per row (80 bytes)
#define RWS 21                   // LDS row stride in words
#define NW (RH*RWW)              // 1640 words

__global__ __launch_bounds__(512) void sim_k(const uint8_t* __restrict__ st_in,
                                             const float* __restrict__ rnd,
                                             float* __restrict__ out) {
    __shared__ uint32_t bufA[RH * RWS];
    __shared__ uint32_t bufB[RH * RWS];
    __shared__ uint32_t aux [RH * RWS];  // per byte: bit0 fall_dir, bit1 did_gravity

    const int tid = threadIdx.x;
    const int b   = blockIdx.z;
    const int h0  = blockIdx.y * TILE;
    const int w0  = blockIdx.x * TILE;
    const uint8_t* stb = st_in + (size_t)b * PLANE;
    const float*   rb  = rnd   + (size_t)b * PLANE;

    // ---- load region (torus wrap; rows are word-aligned, wrap is word-granular) ----
    for (int r = tid; r < NW; r += 512) {
        int i = r / RWW, jw = r - i * RWW;
        int gh  = (h0 + i - HALO_H) & (HH - 1);
        int gwb = (w0 + jw * 4 - HALO_W) & (WW - 1);
        bufA[i * RWS + jw] = *(const uint32_t*)(stb + gh * WW + gwb);
        const float* rp = rb + gh * WW + gwb;
        uint32_t aw = 0;
        aw |= (rp[0] > 0.5f) ? 0x00000001u : 0u;
        aw |= (rp[1] > 0.5f) ? 0x00000100u : 0u;
        aw |= (rp[2] > 0.5f) ? 0x00010000u : 0u;
        aw |= (rp[3] > 0.5f) ? 0x01000000u : 0u;
        aux[i * RWS + jw] = aw;
    }
    __syncthreads();

    // ---- pass 0: stone support / gravity rewrite (zero-padded at global edges) ----
    for (int r = tid; r < NW; r += 512) {
        int i = r / RWW, jw = r - i * RWW;
        uint32_t s = bufA[i * RWS + jw];
        uint32_t stm = eqz4((s & 0x0F0F0F0Fu) ^ 0x09090909u);   // stone bool/byte
        int im = (i > 0) ? i - 1 : 0;
        int jl = (jw > 0) ? jw - 1 : 0;
        int jr = (jw < RWW - 1) ? jw + 1 : RWW - 1;
        uint32_t wU  = bufA[im * RWS + jw];
        uint32_t wUL = bufA[im * RWS + jl];
        uint32_t wUR = bufA[im * RWS + jr];
        uint32_t upL = (wU << 8) | (wUL >> 24);   // above-left bytes
        uint32_t upR = (wU >> 8) | (wUR << 24);   // above-right bytes
        uint32_t stL = eqz4((upL & 0x0F0F0F0Fu) ^ 0x09090909u);
        uint32_t stR = eqz4((upR & 0x0F0F0F0Fu) ^ 0x09090909u);
        int gh  = (h0 + i - HALO_H) & (HH - 1);
        int gwb = (w0 + jw * 4 - HALO_W) & (WW - 1);
        uint32_t rowOK = (gh != 0) ? 0x01010101u : 0u;
        uint32_t okL = 0x01010101u ^ ((gwb == 0)      ? 0x00000001u : 0u); // gw!=0
        uint32_t okR = 0x01010101u ^ ((gwb == WW - 4) ? 0x01000000u : 0u); // gw!=W-1
        uint32_t supL = stL & okL & rowOK;
        uint32_t supR = stR & okR & rowOK;
        uint32_t g2 = 0x01010101u ^ (supL & supR);                // supports < 2
        uint32_t ns = (s & ~0x10101010u) | (g2 << 4);
        bufB[i * RWS + jw] = s ^ ((s ^ ns) & bmask(stm));
    }
    __syncthreads();

    uint32_t* cur = bufB;
    uint32_t* nxt = bufA;

    // ---- passes 1..4: vertical gravity ----
    for (int curr = 0; curr < 4; ++curr) {
        const uint32_t crep = (uint32_t)curr * 0x01010101u;
        for (int r = tid; r < NW; r += 512) {
            int i = r / RWW, jw = r - i * RWW;
            int ia = (i > 0) ? i - 1 : 0;
            int ib = (i < RH - 1) ? i + 1 : RH - 1;
            uint32_t s  = cur[i  * RWS + jw];
            uint32_t sa = cur[ia * RWS + jw];
            uint32_t sb = cur[ib * RWS + jw];
            uint32_t d  = (s  >> 5) & 0x07070707u;
            uint32_t da = (sa >> 5) & 0x07070707u;
            uint32_t db = (sb >> 5) & 0x07070707u;
            uint32_t g  = (s  >> 4) & 0x01010101u;
            uint32_t ga = (sa >> 4) & 0x01010101u;
            uint32_t gb = (sb >> 4) & 0x01010101u;
            uint32_t bel = eqz4(d ^ crep)  & gtb(d, db)  & gb & g;
            uint32_t abv = eqz4(da ^ crep) & gtb(da, d)  & ga & g;
            nxt[i * RWS + jw] = s ^ ((s ^ sb) & bmask(bel)) ^ ((s ^ sa) & bmask(abv));
            aux[i * RWS + jw] |= (abv << 1);
        }
        __syncthreads();
        uint32_t* t = cur; cur = nxt; nxt = t;
    }

    // ---- passes 5..8: diagonal falls (elem,dir) = (2,L),(2,R),(12,L),(12,R) ----
    for (int pass = 0; pass < 4; ++pass) {
        const int  elem = (pass < 2) ? 2 : 12;
        const bool fl   = ((pass & 1) == 0);
        const uint32_t erep = (uint32_t)elem * 0x01010101u;
        for (int r = tid; r < NW; r += 512) {
            int i = r / RWW, jw = r - i * RWW;
            int ia = (i > 0) ? i - 1 : 0;
            int ib = (i < RH - 1) ? i + 1 : RH - 1;
            int jl = (jw > 0) ? jw - 1 : 0;
            int jr = (jw < RWW - 1) ? jw + 1 : RWW - 1;
            uint32_t s   = cur[i * RWS + jw];
            uint32_t wB  = cur[ib * RWS + jw];
            uint32_t wA  = cur[ia * RWS + jw];
            uint32_t aB  = aux[ib * RWS + jw];
            uint32_t aA  = aux[ia * RWS + jw];
            uint32_t sbl, sar, abl, aar;
            if (fl) { // below-left, above-right
                uint32_t wBL = cur[ib * RWS + jl], wAR = cur[ia * RWS + jr];
                uint32_t aBL = aux[ib * RWS + jl], aAR = aux[ia * RWS + jr];
                sbl = (wB << 8) | (wBL >> 24);
                sar = (wA >> 8) | (wAR << 24);
                abl = (aB << 8) | (aBL >> 24);
                aar = (aA >> 8) | (aAR << 24);
            } else {  // below-right, above-left
                uint32_t wBR = cur[ib * RWS + jr], wAL = cur[ia * RWS + jl];
                uint32_t aBR = aux[ib * RWS + jr], aAL = aux[ia * RWS + jl];
                sbl = (wB >> 8) | (wBR << 24);
                sar = (wA << 8) | (wAL >> 24);
                abl = (aB >> 8) | (aBR << 24);
                aar = (aA << 8) | (aAL >> 24);
            }
            uint32_t ax = aux[i * RWS + jw];
            uint32_t d   = (s   >> 5) & 0x07070707u;
            uint32_t dbl = (sbl >> 5) & 0x07070707u;
            uint32_t dar = (sar >> 5) & 0x07070707u;
            uint32_t g   = (s   >> 4) & 0x01010101u;
            uint32_t gbl = (sbl >> 4) & 0x01010101u;
            uint32_t gar = (sar >> 4) & 0x01010101u;
            uint32_t ndg   = ((~ax)  >> 1) & 0x01010101u;
            uint32_t ndgbl = ((~abl) >> 1) & 0x01010101u;
            uint32_t ndgar = ((~aar) >> 1) & 0x01010101u;
            uint32_t mtc = (fl ? ax  : ~ax)  & 0x01010101u;
            uint32_t mta = (fl ? aar : ~aar) & 0x01010101u;
            uint32_t eqe  = eqz4((s   & 0x0F0F0F0Fu) ^ erep);
            uint32_t eqer = eqz4((sar & 0x0F0F0F0Fu) ^ erep);
            uint32_t bbl = eqe  & ndgbl & ndg & mtc & gtb(d, dbl)  & gbl & g;
            uint32_t bar = eqer & ndgar & ndg & mta & gtb(dar, d)  & gar & g;
            nxt[i * RWS + jw] = s ^ ((s ^ sbl) & bmask(bbl)) ^ ((s ^ sar) & bmask(bar));
        }
        __syncthreads();
        uint32_t* t = cur; cur = nxt; nxt = t;
    }

    // ---- expand core 64x64 to 20 f32 channels ----
    float* ob = out + (size_t)b * NCH * PLANE;
    for (int idx = tid; idx < NCH * 64 * 16; idx += 512) {
        int col4 = idx & 15;
        int row  = (idx >> 4) & 63;
        int c    = idx >> 10;
        uint32_t w = cur[(HALO_H + row) * RWS + (HALO_W / 4) + col4];
        float4 v;
        float* vv = &v.x;
#pragma unroll
        for (int q = 0; q < 4; ++q) {
            uint32_t byte = (w >> (8 * q)) & 0xFFu;
            float val;
            if (c < 14)       val = ((byte & 15u) == (uint32_t)c) ? 1.0f : 0.0f;
            else if (c == 14) val = (float)((byte >> 5) & 7u);
            else if (c == 15) val = (float)((byte >> 4) & 1u);
            else              val = 0.0f;
            vv[q] = val;
        }
        *(float4*)(ob + (size_t)c * PLANE + (size_t)(h0 + row) * WW + (w0 + col4 * 4)) = v;
    }
}

extern "C" void kernel_launch(void* const* d_in, const int* in_sizes, int n_in,
                              void* d_out, int out_size, void* d_ws, size_t ws_size,
                              hipStream_t stream) {
    const float* world = (const float*)d_in[0];
    const float* rnd   = (const float*)d_in[1];
    float* out = (float*)d_out;
    uint32_t* st = (uint32_t*)d_ws;   // 2 MB packed byte grid

    extract_k<<<2048, 256, 0, stream>>>(world, st);

    dim3 grid(WW / TILE, HH / TILE, 8);
    sim_k<<<grid, 512, 0, stream>>>((const uint8_t*)st, rnd, out);
}